// Round 8
// baseline (591.031 us; speedup 1.0000x reference)
//
#include <hip/hip_runtime.h>
#include <hip/hip_bf16.h>
#include <cstdint>
#include <cstddef>

#define M_TOTAL 16384   // WORLD_SIZE * M_LOCAL
#define K_DIM   4096
#define N_DIM   4096

typedef __attribute__((ext_vector_type(8))) short s16x8;
typedef __attribute__((ext_vector_type(4))) float f32x4;
typedef __attribute__((ext_vector_type(16))) float f32x16;
typedef unsigned short ushort_t;

// ---------- fp32 -> bf16 round-to-nearest-even ----------
__device__ __forceinline__ ushort_t f2bf(float x) {
  unsigned u = __float_as_uint(x);
  return (ushort_t)((u + 0x7fffu + ((u >> 16) & 1u)) >> 16);
}

// ---------- cast A [M,K] fp32 -> bf16, 8 elems/thread ----------
__global__ __launch_bounds__(256) void cast_kernel(const float* __restrict__ in,
                                                   ushort_t* __restrict__ out,
                                                   long n8) {
  long i = (long)blockIdx.x * 256 + threadIdx.x;
  if (i >= n8) return;
  const f32x4* p = (const f32x4*)in + i * 2;
  f32x4 a = p[0], b = p[1];
  union { s16x8 v; ushort_t u[8]; } r;
  r.u[0] = f2bf(a.x); r.u[1] = f2bf(a.y); r.u[2] = f2bf(a.z); r.u[3] = f2bf(a.w);
  r.u[4] = f2bf(b.x); r.u[5] = f2bf(b.y); r.u[6] = f2bf(b.z); r.u[7] = f2bf(b.w);
  *((s16x8*)out + i) = r.v;
}

// ---------- transpose+cast W [K,N] fp32 -> Bt [N,K] bf16 ----------
__global__ __launch_bounds__(256) void transpose_cast_kernel(const float* __restrict__ B,
                                                             ushort_t* __restrict__ Bt) {
  __shared__ float tile[64][65];
  int nbx = N_DIM / 64;
  int n0 = (blockIdx.x % nbx) * 64;
  int k0 = (blockIdx.x / nbx) * 64;
  int tx = threadIdx.x & 63;
  int ty = threadIdx.x >> 6;
#pragma unroll
  for (int i = 0; i < 64; i += 4)
    tile[ty + i][tx] = B[(size_t)(k0 + ty + i) * N_DIM + n0 + tx];
  __syncthreads();
#pragma unroll
  for (int i = 0; i < 64; i += 4)
    Bt[(size_t)(n0 + ty + i) * K_DIM + k0 + tx] = f2bf(tile[tx][ty + i]);
}

// ============================================================================
// 256x256 bf16 GEMM — round 8: R7's 4-phase/1-barrier structure + 32x32x16
// MFMA (-15% matrix-pipe time vs 16x16x32) with a NEW storage permutation
// engineered so every 32x32 read's bank sequence is XOR-isomorphic to R3's
// empirically-zero-conflict pattern (R4's conflict: constant slot-XOR across
// each 32-lane half; R3-free changes the XOR const every 16 lanes).
//   storage: unit (row, s=s2s1s0) at pslot = (4*s1 + 2*s0 + (rb^s2)) ^ (row&7),
//            rb = (row>>4)&1.  Bijective per row.
//   read (row=R0+(l&31), s=2ks+(l>>5)): pslot = (4(ks&1) + ((2(l>>5)+((l>>4)&1))
//            ^ (ks>>1))) ^ (l&7)  ->  (C + (l>>4 mod 4)-family) ^ (l&7)  [R3 form]
//   stage: linear global_load_lds dest; lane fetches s = 4((y&1)^rb)+2((y>>2)&1)
//            +((y>>1)&1), y = (l&7)^((l>>3)&7), rb = (wid>>1)&1 (wave-uniform).
// Ledger / vmcnt / barriers IDENTICAL to R7. Epilogue = R4's (refcheck-passed).
// ============================================================================
#define BM 256
#define BN 256
#define BK 64
#define NTILE (K_DIM / BK)   // 64 -> 32 iterations, last peeled

__device__ __forceinline__ void load_lds16(const ushort_t* g, ushort_t* l) {
  __builtin_amdgcn_global_load_lds(
      (const __attribute__((address_space(1))) unsigned int*)g,
      (__attribute__((address_space(3))) unsigned int*)l, 16, 0, 0);
}

#define BAR __builtin_amdgcn_s_barrier()
#define VMW4 asm volatile("s_waitcnt vmcnt(4)" ::: "memory")
#define VMW0 asm volatile("s_waitcnt vmcnt(0)" ::: "memory")
#define PRIO1 __builtin_amdgcn_s_setprio(1)
#define PRIO0 __builtin_amdgcn_s_setprio(0)

#define STAGE_A(dst, h, t) do { \
    load_lds16(pA + (size_t)((h) * 128) * K_DIM + (t) * 64, (dst) + (h) * 8192); \
    load_lds16(pA + (size_t)((h) * 128 + 64) * K_DIM + (t) * 64, (dst) + (h) * 8192 + 4096); } while (0)
#define STAGE_B(dst, h, t) do { \
    load_lds16(pB + (size_t)((h) * 128) * K_DIM + (t) * 64, (dst) + (h) * 8192); \
    load_lds16(pB + (size_t)((h) * 128 + 64) * K_DIM + (t) * 64, (dst) + (h) * 8192 + 4096); } while (0)

// ks-dependent slot XOR (ushort units): xk*8, xk = (ks&1)*4 | (ks>>1) -> {0,32,8,40}
#define XK(ks) (((((ks) & 1) * 4) | ((ks) >> 1)) * 8)

// A 32x32 frags: 2 mf x 4 ks b128; arr[2][4]
#define READ_A32(buf, arr, q, mf0) do { \
    _Pragma("unroll") for (int mi = 0; mi < 2; ++mi) \
    _Pragma("unroll") for (int ks = 0; ks < 4; ++ks) \
      arr[mi][ks] = *(const s16x8*)&lds[buf][ (aBase + (q) * 4096 + ((mf0) + mi) * 2048) ^ XK(ks) ]; } while (0)
// B 32x32 frags: 2 nh x 4 ks b128; arr[2][4]
#define READ_B32(buf, arr) do { \
    _Pragma("unroll") for (int nh = 0; nh < 2; ++nh) \
    _Pragma("unroll") for (int ks = 0; ks < 4; ++ks) \
      arr[nh][ks] = *(const s16x8*)&lds[buf][ (bBase + nh * 2048) ^ XK(ks) ]; } while (0)

// 16 MFMA: ks outer, (mi, nf) inner -> 4 independent accs between reuse
#define MFMA32(aa, bb, mb) do { \
    _Pragma("unroll") for (int ks = 0; ks < 4; ++ks) \
    _Pragma("unroll") for (int mi = 0; mi < 2; ++mi) \
    _Pragma("unroll") for (int nf = 0; nf < 2; ++nf) \
      acc[(mb) + mi][nf] = __builtin_amdgcn_mfma_f32_32x32x16_bf16( \
          aa[mi][ks], bb[nf][ks], acc[(mb) + mi][nf], 0, 0, 0); } while (0)

__global__ __launch_bounds__(512, 2)
void gemm_4phase(const ushort_t* __restrict__ A, const ushort_t* __restrict__ Bt,
                 const float* __restrict__ bias, float* __restrict__ C) {
  __shared__ ushort_t lds[2][32768];  // [buf][ A: 0..16383 | B: 16384..32767 ]

  // bijective XCD swizzle (nwg = 1024, % 8 == 0)
  int nwg = gridDim.x;
  int wg  = blockIdx.x;
  int swz = (wg & 7) * (nwg >> 3) + (wg >> 3);
  int bm = (swz >> 4) << 8;
  int bn = (swz & 15) << 8;

  int tid = threadIdx.x;
  int wid = tid >> 6;
  int l   = tid & 63;
  int wm = wid >> 2, wn = wid & 3;

  // ---- staging source permutation (inverse of storage pslot map) ----
  // phys (row = r0 + (l>>3), pslot = l&7) holds logical slot s:
  //   y = (l&7) ^ ((l>>3)&7); rb = (wid>>1)&1 (bit4 of row, wave-uniform);
  //   s = 4*((y&1)^rb) + 2*((y>>2)&1) + ((y>>1)&1)
  int y = (l & 7) ^ ((l >> 3) & 7);
  int rbw = (wid >> 1) & 1;
  int sslot = 4 * ((y & 1) ^ rbw) + 2 * ((y >> 2) & 1) + ((y >> 1) & 1);
  int sg8 = sslot << 3;
  const ushort_t* pA = A  + (size_t)(bm + wid * 8 + (l >> 3)) * K_DIM + sg8;
  const ushort_t* pB = Bt + (size_t)(bn + wid * 8 + (l >> 3)) * K_DIM + sg8;
  ushort_t* sA0 = &lds[0][wid * 512];
  ushort_t* sA1 = &lds[1][wid * 512];
  ushort_t* sB0 = &lds[0][16384 + wid * 512];
  ushort_t* sB1 = &lds[1][16384 + wid * 512];

  // ---- read bases (32x32 frags) ----
  // pslot(ks=0) = (2*(l>>5) + ((l>>4)&1)) ^ (l&7); other ks via ^XK(ks)
  int tt = 2 * (l >> 5) + ((l >> 4) & 1);
  int psl0 = tt ^ (l & 7);
  int aBase = (wm * 128 + (l & 31)) * 64 + psl0 * 8;
  int bBase = 16384 + (wn * 64 + (l & 31)) * 64 + psl0 * 8;

  f32x16 acc[4][2];
#pragma unroll
  for (int im = 0; im < 4; ++im)
#pragma unroll
    for (int nf = 0; nf < 2; ++nf)
#pragma unroll
      for (int e = 0; e < 16; ++e) acc[im][nf][e] = 0.f;

  s16x8 a[2][4], b[2][4];

  // prologue: tile0 full (8 loads), tile1 B (4 loads); drain tile0 (leave B(t1))
  STAGE_B(sB0, 0, 0); STAGE_B(sB0, 1, 0);
  STAGE_A(sA0, 0, 0); STAGE_A(sA0, 1, 0);
  STAGE_B(sB1, 0, 1); STAGE_B(sB1, 1, 1);
  VMW4; BAR;

  for (int j = 0; j < NTILE / 2 - 1; ++j) {   // j = 0..30, tiles 0..61
    int t1 = 2 * j + 1, t2 = 2 * j + 2, t3 = 2 * j + 3;
    // PA1: tile 2j (buf0), mf 0-1 x both nf
    READ_A32(0, a, 0, 0); READ_B32(0, b);
    STAGE_A(sA1, 0, t1); STAGE_A(sA1, 1, t1);
    PRIO1; MFMA32(a, b, 0); PRIO0;
    BAR;
    // PB1: tile 2j, mf 2-3; drain A(t1)
    READ_A32(0, a, 1, 0);
    STAGE_B(sB0, 0, t2); STAGE_B(sB0, 1, t2);
    PRIO1; MFMA32(a, b, 2); PRIO0;
    VMW4; BAR;
    // PA2: tile 2j+1 (buf1), mf 0-1
    READ_A32(1, a, 0, 0); READ_B32(1, b);
    STAGE_A(sA0, 0, t2); STAGE_A(sA0, 1, t2);
    PRIO1; MFMA32(a, b, 0); PRIO0;
    BAR;
    // PB2: tile 2j+1, mf 2-3; drain B(t2),A(t2)
    READ_A32(1, a, 1, 0);
    STAGE_B(sB1, 0, t3); STAGE_B(sB1, 1, t3);
    PRIO1; MFMA32(a, b, 2); PRIO0;
    VMW4; BAR;
  }

  // tail: tiles 62 (buf0), 63 (buf1); B(63) staged in j=30's PB2
  {
    READ_A32(0, a, 0, 0); READ_B32(0, b);
    STAGE_A(sA1, 0, 63); STAGE_A(sA1, 1, 63);
    PRIO1; MFMA32(a, b, 0); PRIO0;
    BAR;

    READ_A32(0, a, 1, 0);
    PRIO1; MFMA32(a, b, 2); PRIO0;
    VMW0; BAR;   // drain A(63)

    READ_A32(1, a, 0, 0); READ_B32(1, b);
    PRIO1; MFMA32(a, b, 0); PRIO0;
    BAR;

    READ_A32(1, a, 1, 0);
    PRIO1; MFMA32(a, b, 2); PRIO0;
  }

  // epilogue: 32x32 C/D layout col=lane&31, row=(reg&3)+8*(reg>>2)+4*(lane>>5)
  // (identical to R4's refcheck-passed epilogue)
  int rBase = bm + wm * 128 + 4 * (l >> 5);
  int cBase = bn + wn * 64 + (l & 31);
#pragma unroll
  for (int nf = 0; nf < 2; ++nf) {
    int c = cBase + nf * 32;
    float bv = bias[c];
#pragma unroll
    for (int im = 0; im < 4; ++im) {
#pragma unroll
      for (int r = 0; r < 16; ++r) {
        int row = rBase + im * 32 + (r & 3) + 8 * (r >> 2);
        C[(size_t)row * N_DIM + c] = acc[im][nf][r] + bv;
      }
    }
  }
}

// ---------- naive fp32 fallback (only if ws_size too small) ----------
__global__ __launch_bounds__(256)
void gemm_naive(const float* __restrict__ A, const float* __restrict__ B,
                const float* __restrict__ bias, float* __restrict__ C) {
  __shared__ float As[64][17];
  __shared__ float Bs[16][65];
  int nbn = N_DIM / 64;
  int m0 = (blockIdx.x / nbn) * 64;
  int n0 = (blockIdx.x % nbn) * 64;
  int tid = threadIdx.x;
  int tx = tid & 15, ty = tid >> 4;
  float acc[4][4] = {};
  for (int k0 = 0; k0 < K_DIM; k0 += 16) {
    __syncthreads();
#pragma unroll
    for (int e = tid * 4, i = 0; i < 4; ++i) {
      int idx = e + i;
      int r = idx >> 4, k = idx & 15;
      As[r][k] = A[(size_t)(m0 + r) * K_DIM + k0 + k];
    }
#pragma unroll
    for (int e = tid * 4, i = 0; i < 4; ++i) {
      int idx = e + i;
      int k = idx >> 6, n = idx & 63;
      Bs[k][n] = B[(size_t)(k0 + k) * N_DIM + n0 + n];
    }
    __syncthreads();
#pragma unroll
    for (int kk = 0; kk < 16; ++kk)
#pragma unroll
      for (int i = 0; i < 4; ++i)
#pragma unroll
        for (int j = 0; j < 4; ++j)
          acc[i][j] += As[ty * 4 + i][kk] * Bs[kk][tx * 4 + j];
  }
#pragma unroll
  for (int i = 0; i < 4; ++i)
#pragma unroll
    for (int j = 0; j < 4; ++j) {
      int r = m0 + ty * 4 + i, c = n0 + tx * 4 + j;
      C[(size_t)r * N_DIM + c] = acc[i][j] + bias[c];
    }
}

extern "C" void kernel_launch(void* const* d_in, const int* in_sizes, int n_in,
                              void* d_out, int out_size, void* d_ws, size_t ws_size,
                              hipStream_t stream) {
  const float* A32  = (const float*)d_in[0];
  const float* W32  = (const float*)d_in[1];
  const float* bias = (const float*)d_in[2];
  float* C = (float*)d_out;

  const size_t needA = (size_t)M_TOTAL * K_DIM * sizeof(ushort_t); // 128 MiB
  const size_t needB = (size_t)N_DIM * K_DIM * sizeof(ushort_t);   // 32 MiB

  if (ws_size >= needA + needB) {
    ushort_t* Abf = (ushort_t*)d_ws;
    ushort_t* Btb = (ushort_t*)((char*)d_ws + needA);
    long n8 = (long)M_TOTAL * K_DIM / 8;
    cast_kernel<<<(int)((n8 + 255) / 256), 256, 0, stream>>>(A32, Abf, n8);
    transpose_cast_kernel<<<(K_DIM / 64) * (N_DIM / 64), 256, 0, stream>>>(W32, Btb);
    gemm_4phase<<<(M_TOTAL / BM) * (N_DIM / BN), 512, 0, stream>>>(Abf, Btb, bias, C);
  } else {
    gemm_naive<<<(M_TOTAL / 64) * (N_DIM / 64), 256, 0, stream>>>(A32, W32, bias, C);
  }
}

// Round 9
// 560.030 us; speedup vs baseline: 1.0554x; 1.0554x over previous
//
#include <hip/hip_runtime.h>
#include <hip/hip_bf16.h>
#include <cstdint>
#include <cstddef>

#define M_TOTAL 16384   // WORLD_SIZE * M_LOCAL
#define K_DIM   4096
#define N_DIM   4096

typedef __attribute__((ext_vector_type(8))) short s16x8;
typedef __attribute__((ext_vector_type(4))) float f32x4;
typedef unsigned short ushort_t;

// ---------- fp32 -> bf16 round-to-nearest-even ----------
__device__ __forceinline__ ushort_t f2bf(float x) {
  unsigned u = __float_as_uint(x);
  return (ushort_t)((u + 0x7fffu + ((u >> 16) & 1u)) >> 16);
}

// ---------- cast A [M,K] fp32 -> bf16, 8 elems/thread ----------
__global__ __launch_bounds__(256) void cast_kernel(const float* __restrict__ in,
                                                   ushort_t* __restrict__ out,
                                                   long n8) {
  long i = (long)blockIdx.x * 256 + threadIdx.x;
  if (i >= n8) return;
  const f32x4* p = (const f32x4*)in + i * 2;
  f32x4 a = p[0], b = p[1];
  union { s16x8 v; ushort_t u[8]; } r;
  r.u[0] = f2bf(a.x); r.u[1] = f2bf(a.y); r.u[2] = f2bf(a.z); r.u[3] = f2bf(a.w);
  r.u[4] = f2bf(b.x); r.u[5] = f2bf(b.y); r.u[6] = f2bf(b.z); r.u[7] = f2bf(b.w);
  *((s16x8*)out + i) = r.v;
}

// ---------- transpose+cast W [K,N] fp32 -> Bt [N,K] bf16 ----------
__global__ __launch_bounds__(256) void transpose_cast_kernel(const float* __restrict__ B,
                                                             ushort_t* __restrict__ Bt) {
  __shared__ float tile[64][65];
  int nbx = N_DIM / 64;
  int n0 = (blockIdx.x % nbx) * 64;
  int k0 = (blockIdx.x / nbx) * 64;
  int tx = threadIdx.x & 63;
  int ty = threadIdx.x >> 6;
#pragma unroll
  for (int i = 0; i < 64; i += 4)
    tile[ty + i][tx] = B[(size_t)(k0 + ty + i) * N_DIM + n0 + tx];
  __syncthreads();
#pragma unroll
  for (int i = 0; i < 64; i += 4)
    Bt[(size_t)(n0 + ty + i) * K_DIM + k0 + tx] = f2bf(tile[tx][ty + i]);
}

// ============================================================================
// 256x256 bf16 GEMM — round 9: R7 (16x16x32, 0-conflict, counted vmcnt) with
// ONE barrier per K-tile (2/iter, was 4) via B TRIPLE-BUFFER.
// R7's mid-tile barrier only protected B(t+2) staging into the just-read B
// 2-buffer. With B x3: B(t+2)->Bbuf((t+2)%3) was last read at tile t-1 and
// published by barrier(t-1) -> staging is safe anywhere in tile t -> the
// mid-tile barrier protects nothing and is removed.
// LDS: A x2 (64KB) + B x3 (96KB) = 160KB exactly (full CU LDS; AITER uses
// 160KB blocks on gfx950).
// Per-tile phase: {read q0+B (16 b128); stage A(t+1) (4 loads); 32 MFMA;
//                  read q1 (8, reusing a[]); stage B(t+2) (4); 32 MFMA;
//                  VMW4; BAR}
// VMW4 ledger at tile t: outstanding [B(t+1)4, A(t+1)4, B(t+2)4]=12 ->
// drains B(t+1),A(t+1) (needed next tile), leaves B(t+2) counted in flight.
// Buffer period lcm(2,3)=6 -> 6-tile unrolled body x10 (t=0..59) + 4 peeled.
// Reads / MFMA order / XOR swizzle / epilogue byte-identical to R7.
// ============================================================================
#define BM 256
#define BN 256
#define BK 64
#define NTILE (K_DIM / BK)   // 64

__device__ __forceinline__ void load_lds16(const ushort_t* g, ushort_t* l) {
  __builtin_amdgcn_global_load_lds(
      (const __attribute__((address_space(1))) unsigned int*)g,
      (__attribute__((address_space(3))) unsigned int*)l, 16, 0, 0);
}

#define BAR __builtin_amdgcn_s_barrier()
#define VMW4 asm volatile("s_waitcnt vmcnt(4)" ::: "memory")
#define VMW0 asm volatile("s_waitcnt vmcnt(0)" ::: "memory")
#define PRIO1 __builtin_amdgcn_s_setprio(1)
#define PRIO0 __builtin_amdgcn_s_setprio(0)

#define STAGE_A(dst, h, t) do { \
    load_lds16(pA + (size_t)((h) * 128) * K_DIM + (size_t)(t) * 64, (dst) + (h) * 8192); \
    load_lds16(pA + (size_t)((h) * 128 + 64) * K_DIM + (size_t)(t) * 64, (dst) + (h) * 8192 + 4096); } while (0)
#define STAGE_B(dst, h, t) do { \
    load_lds16(pB + (size_t)((h) * 128) * K_DIM + (size_t)(t) * 64, (dst) + (h) * 8192); \
    load_lds16(pB + (size_t)((h) * 128 + 64) * K_DIM + (size_t)(t) * 64, (dst) + (h) * 8192 + 4096); } while (0)

#define READ_A(AB, arr, q) do { \
    _Pragma("unroll") for (int mf = 0; mf < 4; ++mf) { \
      int ia = aBase + ((q) * 4 + mf) * 1024; \
      arr[mf][0] = *(const s16x8*)&lds_a[AB][ia]; \
      arr[mf][1] = *(const s16x8*)&lds_a[AB][ia ^ 32]; } } while (0)
#define READ_B(BB, arr, nh) do { \
    _Pragma("unroll") for (int nf = 0; nf < 2; ++nf) { \
      int ib = bBase + ((nh) * 2 + nf) * 1024; \
      arr[nf][0] = *(const s16x8*)&lds_b[BB][ib]; \
      arr[nf][1] = *(const s16x8*)&lds_b[BB][ib ^ 32]; } } while (0)

// 16 MFMA, ks outermost: 8 independent between accumulator reuse.
#define MFMA_Q(arr_a, arr_b, m0, n0) do { \
    _Pragma("unroll") for (int ks = 0; ks < 2; ++ks) \
    _Pragma("unroll") for (int mf = 0; mf < 4; ++mf) \
    _Pragma("unroll") for (int nf = 0; nf < 2; ++nf) \
      acc[(m0) + mf][(n0) + nf] = __builtin_amdgcn_mfma_f32_16x16x32_bf16( \
          arr_a[mf][ks], arr_b[nf][ks], acc[(m0) + mf][(n0) + nf], 0, 0, 0); } while (0)

// One K-tile: buffers AB/BB (literals), stage A(TA)->aP<ABN>, B(TB)->bP<BBN>
#define TILE_FULL(AB, BB, ABN, BBN, TA, TB) do { \
    READ_A(AB, a, 0); READ_B(BB, b0, 0); READ_B(BB, b1, 1); \
    STAGE_A(aP##ABN, 0, (TA)); STAGE_A(aP##ABN, 1, (TA)); \
    PRIO1; MFMA_Q(a, b0, 0, 0); MFMA_Q(a, b1, 0, 2); PRIO0; \
    READ_A(AB, a, 1); \
    STAGE_B(bP##BBN, 0, (TB)); STAGE_B(bP##BBN, 1, (TB)); \
    PRIO1; MFMA_Q(a, b1, 4, 2); MFMA_Q(a, b0, 4, 0); PRIO0; \
    VMW4; BAR; \
  } while (0)

__global__ __launch_bounds__(512, 2)
void gemm_1bar(const ushort_t* __restrict__ A, const ushort_t* __restrict__ Bt,
               const float* __restrict__ bias, float* __restrict__ C) {
  __shared__ ushort_t lds_a[2][16384];   // 64 KiB
  __shared__ ushort_t lds_b[3][16384];   // 96 KiB  (total 160 KiB)

  // bijective XCD swizzle (nwg = 1024, % 8 == 0)
  int nwg = gridDim.x;
  int wg  = blockIdx.x;
  int swz = (wg & 7) * (nwg >> 3) + (wg >> 3);
  int bm = (swz >> 4) << 8;
  int bn = (swz & 15) << 8;

  int tid = threadIdx.x;
  int wid = tid >> 6;
  int l   = tid & 63;
  int wm = wid >> 2, wn = wid & 3;

  // staging: lane covers global (row = base + wid*8 + (l>>3), slot = (l&7)^(row&7))
  int sg8 = ((l & 7) ^ ((l >> 3) & 7)) << 3;
  const ushort_t* pA = A  + (size_t)(bm + wid * 8 + (l >> 3)) * K_DIM + sg8;
  const ushort_t* pB = Bt + (size_t)(bn + wid * 8 + (l >> 3)) * K_DIM + sg8;
  ushort_t* aP0 = &lds_a[0][wid * 512];
  ushort_t* aP1 = &lds_a[1][wid * 512];
  ushort_t* bP0 = &lds_b[0][wid * 512];
  ushort_t* bP1 = &lds_b[1][wid * 512];
  ushort_t* bP2 = &lds_b[2][wid * 512];

  // read bases: row = (wm*128 | mf*16 | (l&15)); slot = (ks*4 | (l>>4)) ^ (l&7)
  int slot0 = (l >> 4) ^ (l & 7);
  int aBase = (wm * 128 + (l & 15)) * 64 + slot0 * 8;
  int bBase = (wn * 64 + (l & 15)) * 64 + slot0 * 8;

  f32x4 acc[8][4];
#pragma unroll
  for (int mf = 0; mf < 8; ++mf)
#pragma unroll
    for (int nf = 0; nf < 4; ++nf) acc[mf][nf] = (f32x4){0.f, 0.f, 0.f, 0.f};

  s16x8 a[4][2], b0[2][2], b1[2][2];

  // prologue: A(0)->Ab0, B(0)->Bb0 (8 loads), B(1)->Bb1 (4);
  // VMW4 drains A(0),B(0), leaves B(1) in flight; BAR publishes tile 0.
  STAGE_A(aP0, 0, 0); STAGE_A(aP0, 1, 0);
  STAGE_B(bP0, 0, 0); STAGE_B(bP0, 1, 0);
  STAGE_B(bP1, 0, 1); STAGE_B(bP1, 1, 1);
  VMW4; BAR;

  // t = 0..59 (6-tile period: A t&1, B t%3)
  for (int r = 0; r < 10; ++r) {
    int t = 6 * r;
    TILE_FULL(0, 0, 1, 2, t + 1, t + 2);   // t%6==0
    TILE_FULL(1, 1, 0, 0, t + 2, t + 3);   // 1
    TILE_FULL(0, 2, 1, 1, t + 3, t + 4);   // 2
    TILE_FULL(1, 0, 0, 2, t + 4, t + 5);   // 3
    TILE_FULL(0, 1, 1, 0, t + 5, t + 6);   // 4
    TILE_FULL(1, 2, 0, 1, t + 6, t + 7);   // 5
  }
  // t=60 (Ab0,Bb0): stage A(61)->Ab1, B(62)->Bb2
  TILE_FULL(0, 0, 1, 2, 61, 62);
  // t=61 (Ab1,Bb1): stage A(62)->Ab0, B(63)->Bb0
  TILE_FULL(1, 1, 0, 0, 62, 63);
  // t=62 (Ab0,Bb2): stage A(63)->Ab1; full drain
  {
    READ_A(0, a, 0); READ_B(2, b0, 0); READ_B(2, b1, 1);
    STAGE_A(aP1, 0, 63); STAGE_A(aP1, 1, 63);
    PRIO1; MFMA_Q(a, b0, 0, 0); MFMA_Q(a, b1, 0, 2); PRIO0;
    READ_A(0, a, 1);
    PRIO1; MFMA_Q(a, b1, 4, 2); MFMA_Q(a, b0, 4, 0); PRIO0;
    VMW0; BAR;   // A(63),B(63) landed + published
  }
  // t=63 (Ab1,Bb0): reads only
  {
    READ_A(1, a, 0); READ_B(0, b0, 0); READ_B(0, b1, 1);
    PRIO1; MFMA_Q(a, b0, 0, 0); MFMA_Q(a, b1, 0, 2); PRIO0;
    READ_A(1, a, 1);
    PRIO1; MFMA_Q(a, b1, 4, 2); MFMA_Q(a, b0, 4, 0); PRIO0;
  }

  // epilogue: C/D layout col = lane&15, row = (lane>>4)*4 + j
  int r0 = bm + wm * 128 + ((l >> 4) << 2);
  int c0 = bn + wn * 64 + (l & 15);
#pragma unroll
  for (int nf = 0; nf < 4; ++nf) {
    float bv = bias[c0 + nf * 16];
#pragma unroll
    for (int mf = 0; mf < 8; ++mf) {
#pragma unroll
      for (int jj = 0; jj < 4; ++jj)
        C[(size_t)(r0 + mf * 16 + jj) * N_DIM + (c0 + nf * 16)] = acc[mf][nf][jj] + bv;
    }
  }
}

// ---------- naive fp32 fallback (only if ws_size too small) ----------
__global__ __launch_bounds__(256)
void gemm_naive(const float* __restrict__ A, const float* __restrict__ B,
                const float* __restrict__ bias, float* __restrict__ C) {
  __shared__ float As[64][17];
  __shared__ float Bs[16][65];
  int nbn = N_DIM / 64;
  int m0 = (blockIdx.x / nbn) * 64;
  int n0 = (blockIdx.x % nbn) * 64;
  int tid = threadIdx.x;
  int tx = tid & 15, ty = tid >> 4;
  float acc[4][4] = {};
  for (int k0 = 0; k0 < K_DIM; k0 += 16) {
    __syncthreads();
#pragma unroll
    for (int e = tid * 4, i = 0; i < 4; ++i) {
      int idx = e + i;
      int r = idx >> 4, k = idx & 15;
      As[r][k] = A[(size_t)(m0 + r) * K_DIM + k0 + k];
    }
#pragma unroll
    for (int e = tid * 4, i = 0; i < 4; ++i) {
      int idx = e + i;
      int k = idx >> 6, n = idx & 63;
      Bs[k][n] = B[(size_t)(k0 + k) * N_DIM + n0 + n];
    }
    __syncthreads();
#pragma unroll
    for (int kk = 0; kk < 16; ++kk)
#pragma unroll
      for (int i = 0; i < 4; ++i)
#pragma unroll
        for (int j = 0; j < 4; ++j)
          acc[i][j] += As[ty * 4 + i][kk] * Bs[kk][tx * 4 + j];
  }
#pragma unroll
  for (int i = 0; i < 4; ++i)
#pragma unroll
    for (int j = 0; j < 4; ++j) {
      int r = m0 + ty * 4 + i, c = n0 + tx * 4 + j;
      C[(size_t)r * N_DIM + c] = acc[i][j] + bias[c];
    }
}

extern "C" void kernel_launch(void* const* d_in, const int* in_sizes, int n_in,
                              void* d_out, int out_size, void* d_ws, size_t ws_size,
                              hipStream_t stream) {
  const float* A32  = (const float*)d_in[0];
  const float* W32  = (const float*)d_in[1];
  const float* bias = (const float*)d_in[2];
  float* C = (float*)d_out;

  const size_t needA = (size_t)M_TOTAL * K_DIM * sizeof(ushort_t); // 128 MiB
  const size_t needB = (size_t)N_DIM * K_DIM * sizeof(ushort_t);   // 32 MiB

  if (ws_size >= needA + needB) {
    ushort_t* Abf = (ushort_t*)d_ws;
    ushort_t* Btb = (ushort_t*)((char*)d_ws + needA);
    long n8 = (long)M_TOTAL * K_DIM / 8;
    cast_kernel<<<(int)((n8 + 255) / 256), 256, 0, stream>>>(A32, Abf, n8);
    transpose_cast_kernel<<<(K_DIM / 64) * (N_DIM / 64), 256, 0, stream>>>(W32, Btb);
    gemm_1bar<<<(M_TOTAL / BM) * (N_DIM / BN), 512, 0, stream>>>(Abf, Btb, bias, C);
  } else {
    gemm_naive<<<(M_TOTAL / 64) * (N_DIM / 64), 256, 0, stream>>>(A32, W32, bias, C);
  }
}